// Round 20
// baseline (226.384 us; speedup 1.0000x reference)
//
#include <hip/hip_runtime.h>
#include <hip/hip_bf16.h>

// ---- types ----
typedef __attribute__((ext_vector_type(8))) short v8s;   // 8 x bf16
typedef __attribute__((ext_vector_type(4))) float v4f;
typedef __attribute__((ext_vector_type(16))) float v16f; // 32x32 MFMA C/D
typedef __attribute__((ext_vector_type(4))) unsigned v4u;

#define S_LEN 2048
#define NB 4
#define NH 16
#define LOG2E 1.4426950408889634f
// Mask constant: 1.3125 * 2^40 — EXACTLY representable in bf16 AND fp32.
#define CMASK 1443109011456.0f
#define DEFER_THR 11.55f                // ~8 * log2(e)  (T13)

__device__ __forceinline__ short f2bf(float f) {
    __hip_bfloat16 h = __float2bfloat16(f);
    union { __hip_bfloat16 h; short s; } u; u.h = h; return u.s;
}

__device__ __forceinline__ unsigned cvtpk(float lo, float hi) {
    unsigned r;
    asm("v_cvt_pk_bf16_f32 %0, %1, %2" : "=v"(r) : "v"(lo), "v"(hi));
    return r;
}

// XOR swizzle for [R][128B] LDS tiles (read side). A-tile: write-side swizzle
// via ds_write to swz() addr (natural source chunk); B-tile: pre-swizzled
// gload_lds SOURCE chunk (rule #21). Both produce the same physical layout.
__device__ __forceinline__ int swz(int row, int col) {
    return (row * 128 + col) ^ ((row & 7) << 4);
}

__device__ __forceinline__ void async16(void* lds, const void* g) {
    __builtin_amdgcn_global_load_lds(
        (const __attribute__((address_space(1))) unsigned int*)g,
        (__attribute__((address_space(3))) unsigned int*)lds, 16, 0, 0);
}

#define MFMA16(a, b, c) __builtin_amdgcn_mfma_f32_16x16x32_bf16((a), (b), (c), 0, 0, 0)
#define MFMA32(a, b, c) __builtin_amdgcn_mfma_f32_32x32x16_bf16((a), (b), (c), 0, 0, 0)

// ---------------- zero-fill output (dead q_mask rows are exactly 0) --------
__global__ __launch_bounds__(256) void zero_out(float* __restrict__ out) {
    size_t i = ((size_t)blockIdx.x * 256 + threadIdx.x) * 16;
    float4 z = {0.f, 0.f, 0.f, 0.f};
#pragma unroll
    for (int k = 0; k < 4; ++k) *(float4*)(out + i + k * 4) = z;
}

// ---------------- penalty column: pen[b][s] = vm ? 0 : -CMASK (bf16) -------
__global__ __launch_bounds__(256) void build_pen(const int* __restrict__ vm,
                                                 short* __restrict__ penC) {
    int i = blockIdx.x * 256 + threadIdx.x;   // 8192 total
    penC[i] = vm[i] ? (short)0 : f2bf(-CMASK);
}

// ------------- q_mask compaction: idx[b][j] = j-th live row, nq[b] ---------
__global__ __launch_bounds__(256) void compact_qmask(const int* __restrict__ qm,
                                                     int* __restrict__ idx,
                                                     int* __restrict__ nq) {
    const int b = blockIdx.x;
    const int* m = qm + b * S_LEN;
    int* ib = idx + b * S_LEN;
    __shared__ int cnt[256];
    const int t = threadIdx.x;
    int loc[8], c = 0;
#pragma unroll
    for (int i = 0; i < 8; ++i) { int s = t * 8 + i; if (m[s]) loc[c++] = s; }
    cnt[t] = c;
    __syncthreads();
    for (int d = 1; d < 256; d <<= 1) {       // Hillis-Steele inclusive scan
        int v = (t >= d) ? cnt[t - d] : 0;
        __syncthreads();
        cnt[t] += v;
        __syncthreads();
    }
    int off = cnt[t] - c;                     // exclusive prefix
    for (int i = 0; i < c; ++i) ib[off + i] = loc[i];
    if (t == 255) nq[b] = cnt[255];
}

// ---------------- fused W[K][N] fp32 -> WT[N][K] bf16 (4 weights) ----------
__global__ __launch_bounds__(256) void transpose_all(const float* __restrict__ Wq,
                                                     const float* __restrict__ Wk,
                                                     const float* __restrict__ Wv,
                                                     const float* __restrict__ Wo,
                                                     short* __restrict__ WTq,
                                                     short* __restrict__ WTk,
                                                     short* __restrict__ WTv,
                                                     short* __restrict__ WTo) {
    const int z = blockIdx.z;
    const float* W = (z == 0) ? Wq : (z == 1) ? Wk : (z == 2) ? Wv : Wo;
    short* WT = (z == 0) ? WTq : (z == 1) ? WTk : (z == 2) ? WTv : WTo;
    __shared__ float tile[32][33];
    int k0 = blockIdx.x * 32, n0 = blockIdx.y * 32;
    int tx = threadIdx.x & 31, ty = threadIdx.x >> 5;  // ty 0..7
#pragma unroll
    for (int i = 0; i < 4; ++i)
        tile[ty + i * 8][tx] = W[(size_t)(k0 + ty + i * 8) * 1024 + n0 + tx];
    __syncthreads();
#pragma unroll
    for (int i = 0; i < 4; ++i)
        WT[(size_t)(n0 + ty + i * 8) * 1024 + k0 + tx] = f2bf(tile[tx][ty + i * 8]);
}

// ---------------- unified projection GEMM: z=0 K, z=1 V, z=2 Q-compacted ---
// XCD-aware bijective map (T1) + LDS XOR-swizzle (G4) + dbuf/counted-vmcnt
// (R19). NEW (R20): FUSED fp32->bf16 CONVERT — A staged directly from the
// fp32 inputs via reg-staging (8x dwordx4/thread, double-buffered regs,
// rule #20 static names) + cvt_pk + ds_write to the swizzled LDS address.
// Kills the entire convert_all pass (~29 µs: 100MB read + 50MB write + the
// 50MB re-read here). Ledger: stage issues 4 gload_lds(B) + 8 dwordx4(A)
// = 12 VMEM -> vmcnt(12) retires all of tile kt. lgkmcnt(0) before B2
// (raw s_barrier does not drain DS writes).
__global__ __launch_bounds__(256)
void proj_all(const float* __restrict__ kI, const float* __restrict__ vI,
              const float* __restrict__ qI,
              const short* __restrict__ WTk, const short* __restrict__ WTv,
              const short* __restrict__ WTq,
              const float* __restrict__ bk, const float* __restrict__ bv,
              const float* __restrict__ bq,
              const int* __restrict__ idx, const int* __restrict__ nq,
              short* __restrict__ KF, short* __restrict__ VF,
              short* __restrict__ QW) {
    __shared__ short As[2][128 * 64];
    __shared__ short Bs[2][128 * 64];
    const int tid = threadIdx.x;
    const int l = tid & 63, w = tid >> 6;
    const int g = l >> 4, ql = l & 15;
    const int z = blockIdx.z;
    const int bid = blockIdx.x;
    const int y = (bid & 7) + 8 * (bid >> 6);   // M-tile (XCD-pinned)
    const int n0 = ((bid >> 3) & 7) * 128;      // N-tile (cycles fastest)
    const int wr = w >> 1, wc = w & 1;

    int b = 0, m0 = y * 128, m0c = 0, nqv = 0;
    const int* idxb = nullptr;
    if (z == 2) {
        if (y >= 36) return;
        b = y / 9; m0c = (y % 9) * 128;
        nqv = nq[b];
        if (m0c >= nqv) return;
        idxb = idx + b * S_LEN;
    }
    const float* Af = (z == 0) ? kI : (z == 1) ? vI : qI;
    const short* BT = (z == 0) ? WTk : (z == 1) ? WTv : WTq;
    const float* bias = (z == 0) ? bk : (z == 1) ? bv : bq;

    // per-thread A-row (gathered for Q slice; linear otherwise)
    int arow[4];
#pragma unroll
    for (int i = 0; i < 4; ++i) {
        int row = (i * 256 + tid) >> 3;
        if (z == 2) {
            int jc = m0c + row;
            arow[i] = b * S_LEN + idxb[(jc < nqv) ? jc : (nqv - 1)];
        } else {
            arow[i] = m0 + row;
        }
    }
    const int c8  = (((l & 7) ^ (l >> 3))) * 8;  // B: pre-swizzled src chunk
    const int c8a = (tid & 7) * 8;               // A: natural fp32 src chunk

    v4f acc[4][4] = {};
    float4 f4A[8], f4B[8];                       // A reg double-buffer

    auto issueB = [&](int kt, int buf) {
        const int kk = kt * 64;
#pragma unroll
        for (int i = 0; i < 4; ++i) {
            int ci = i * 256 + tid;
            async16((char*)Bs[buf] + (size_t)ci * 16,
                    BT + (size_t)(n0 + (ci >> 3)) * 1024 + kk + c8);
        }
    };
    auto issueA = [&](int kt, float4* fr) {
        const int kk = kt * 64;
#pragma unroll
        for (int i = 0; i < 4; ++i) {
            const float* src = Af + (size_t)arow[i] * 1024 + kk + c8a;
            fr[2 * i]     = *(const float4*)(src);
            fr[2 * i + 1] = *(const float4*)(src + 4);
        }
    };
    auto writeA = [&](int buf, const float4* fr) {
#pragma unroll
        for (int i = 0; i < 4; ++i) {
            int ci = i * 256 + tid;
            int row = ci >> 3;
            v4u wv;
            wv[0] = cvtpk(fr[2 * i].x, fr[2 * i].y);
            wv[1] = cvtpk(fr[2 * i].z, fr[2 * i].w);
            wv[2] = cvtpk(fr[2 * i + 1].x, fr[2 * i + 1].y);
            wv[3] = cvtpk(fr[2 * i + 1].z, fr[2 * i + 1].w);
            *(v4u*)((char*)As[buf] + swz(row, (tid & 7) * 16)) = wv;
        }
    };

    issueB(0, 0);
    issueA(0, f4A);
    for (int kt = 0; kt < 16; ++kt) {
        __builtin_amdgcn_s_barrier();         // B1: next buf free to write
        __builtin_amdgcn_sched_barrier(0);
        if (kt + 1 < 16) {
            issueB(kt + 1, (kt + 1) & 1);
            if (kt & 1) issueA(kt + 1, f4A);
            else        issueA(kt + 1, f4B);
            asm volatile("s_waitcnt vmcnt(12)" ::: "memory");  // kt's 12 done
        } else {
            asm volatile("s_waitcnt vmcnt(0)" ::: "memory");
        }
        __builtin_amdgcn_sched_barrier(0);
        if (kt & 1) writeA(1, f4B);
        else        writeA(0, f4A);
        asm volatile("s_waitcnt lgkmcnt(0)" ::: "memory");  // drain ds_writes
        __builtin_amdgcn_sched_barrier(0);
        __builtin_amdgcn_s_barrier();         // B2: tile kt staged (all waves)
        __builtin_amdgcn_sched_barrier(0);    // rule #18: no ds_read hoisting
        const short* Ab = As[kt & 1];
        const short* Bb = Bs[kt & 1];
#pragma unroll
        for (int ks = 0; ks < 2; ++ks) {
            v8s af[4], bfr[4];
#pragma unroll
            for (int mt = 0; mt < 4; ++mt)
                af[mt] = *(const v8s*)((char*)Ab +
                          swz(wr * 64 + mt * 16 + ql, ks * 64 + g * 16));
#pragma unroll
            for (int nt = 0; nt < 4; ++nt)
                bfr[nt] = *(const v8s*)((char*)Bb +
                          swz(wc * 64 + nt * 16 + ql, ks * 64 + g * 16));
#pragma unroll
            for (int mt = 0; mt < 4; ++mt)
#pragma unroll
                for (int nt = 0; nt < 4; ++nt)
                    acc[mt][nt] = MFMA16(af[mt], bfr[nt], acc[mt][nt]);
        }
    }

#pragma unroll
    for (int nt = 0; nt < 4; ++nt) {
        int col = n0 + wc * 64 + nt * 16 + ql;
        float bval = bias[col];
        int hh = col >> 6, dd = col & 63;
#pragma unroll
        for (int mt = 0; mt < 4; ++mt) {
#pragma unroll
            for (int r = 0; r < 4; ++r) {
                int lrow = wr * 64 + mt * 16 + g * 4 + r;
                float vv = acc[mt][nt][r] + bval;
                if (z == 0) {
                    int gm = m0 + lrow;
                    int bb = gm >> 11, ss = gm & 2047;
                    // K fragment layout: [bh][kt][ks][row][hi][8]
                    size_t base = (size_t)(bb * NH + hh) * 131072
                                + (size_t)(ss >> 6) * 4096
                                + (dd >> 4) * 1024 + (ss & 63) * 16
                                + ((dd >> 3) & 1) * 8 + (dd & 7);
                    KF[base] = f2bf(vv);
                } else if (z == 1) {
                    int gm = m0 + lrow;
                    int bb = gm >> 11, ss = gm & 2047;
                    // V fragment layout: [bh][kt][ks][d][hi][8] (kp-split)
                    int wkp = ss & 63;
                    size_t base = (size_t)(bb * NH + hh) * 131072
                                + (size_t)(ss >> 6) * 4096
                                + (wkp >> 4) * 1024 + dd * 16
                                + ((wkp >> 3) & 1) * 8 + (wkp & 7);
                    VF[base] = f2bf(vv);
                } else {
                    int jc = m0c + lrow;                 // compacted row
                    vv *= 0.125f * LOG2E;
                    QW[((size_t)(b * NH + hh) * S_LEN + jc) * 64 + dd] = f2bf(vv);
                }
            }
        }
    }
}

// ---------------- flash attention: streaming, fragment-major K/V -----------
// (frozen from R18: 1-wave blocks, no LDS, no barriers, 1KB-contiguous
// fragment loads)
__global__ __launch_bounds__(64)
void attn_kernel(const short* __restrict__ QW, const short* __restrict__ KF,
                 const short* __restrict__ VF, const short* __restrict__ penC,
                 const int* __restrict__ idx, const int* __restrict__ nq,
                 short* __restrict__ O) {
    const int l = threadIdx.x;                // 1 wave
    const int lq = l & 31, hi = l >> 5;
    const int bh = blockIdx.x;
    const int chunk = 63 - (int)blockIdx.y;   // heavy chunks dispatch first
    const int b = bh >> 4, hd = bh & 15;

    const int nqv = nq[b];
    const int cy = chunk * 32;                // compacted base row (32/wave)
    if (cy >= nqv) return;                    // dead chunk retires instantly

    const short* Qp = QW + (size_t)bh * S_LEN * 64;
    const short* Kp = KF + (size_t)bh * 131072;
    const short* Vp = VF + (size_t)bh * 131072;
    const short* pp = penC + b * S_LEN;
    const int* idxb = idx + b * S_LEN;

    const int j = cy + lq;
    const int jj = (j < nqv) ? j : (nqv - 1);
    const int q_glob = idxb[jj];
    const int qmin = __builtin_amdgcn_readfirstlane(q_glob);

    int lastj = cy + 31; if (lastj > nqv - 1) lastj = nqv - 1;
    const int NT = (idxb[lastj] >> 6) + 1;

    // Q fragments from COMPACTED QW
    v8s qf[4];
#pragma unroll
    for (int ks = 0; ks < 4; ++ks)
        qf[ks] = *(const v8s*)(Qp + (size_t)jj * 64 + ks * 16 + hi * 8);
    v8s qf4 = {};
    qf4[0] = hi ? (short)0 : (short)0x3F80;   // bf16(1.0) at virtual k=64

    v16f accO[2] = {};
    float m_run = -INFINITY, l_run = 0.f;

    auto tile = [&](int kt, bool causal) {
        const int k0 = kt * 64;
        const short* Kt = Kp + (size_t)kt * 4096;
        const short* Vt = Vp + (size_t)kt * 4096;
        short p0 = pp[k0 + lq], p1 = pp[k0 + lq + 32];

        // K fragments: 1KB contiguous per load (fragment-major layout)
        v8s kf0[4], kf1[4];
#pragma unroll
        for (int ks = 0; ks < 4; ++ks) {
            kf0[ks] = *(const v8s*)(Kt + ks * 1024 + lq * 16 + hi * 8);
            kf1[ks] = *(const v8s*)(Kt + ks * 1024 + (lq + 32) * 16 + hi * 8);
        }
        v16f acc0 = {}, acc1 = {};
        __builtin_amdgcn_s_setprio(1);
#pragma unroll
        for (int ks = 0; ks < 4; ++ks) {
            acc0 = MFMA32(kf0[ks], qf[ks], acc0);
            acc1 = MFMA32(kf1[ks], qf[ks], acc1);
        }
        // 5th slice: v_mask penalty column (hi=0 lanes carry pen at k=64)
        v8s k4a = {}, k4b = {};
        k4a[0] = hi ? (short)0 : p0;
        k4b[0] = hi ? (short)0 : p1;
        acc0 = MFMA32(k4a, qf4, acc0);
        acc1 = MFMA32(k4b, qf4, acc1);
        __builtin_amdgcn_s_setprio(0);

        float s[32];
#pragma unroll
        for (int jn = 0; jn < 16; ++jn) { s[jn] = acc0[jn]; s[16 + jn] = acc1[jn]; }
        if (causal) {
#pragma unroll
            for (int t = 0; t < 2; ++t)
#pragma unroll
                for (int jn = 0; jn < 16; ++jn) {
                    int kp = k0 + t * 32 + (jn & 3) + 8 * (jn >> 2) + 4 * hi;
                    if (kp > q_glob) s[t * 16 + jn] -= CMASK;
                }
        }
        // tree max (depth 5)
        float t8[8];
#pragma unroll
        for (int i = 0; i < 8; ++i)
            t8[i] = fmaxf(fmaxf(s[i], s[i + 8]), fmaxf(s[i + 16], s[i + 24]));
#pragma unroll
        for (int i = 0; i < 4; ++i) t8[i] = fmaxf(t8[i], t8[i + 4]);
        float tmax = fmaxf(fmaxf(t8[0], t8[1]), fmaxf(t8[2], t8[3]));
        tmax = fmaxf(tmax, __shfl_xor(tmax, 32, 64));   // cross-half

        // T13 defer-max
        if (__any(tmax > m_run + DEFER_THR)) {
            float mnew = fmaxf(m_run, tmax);
            float scale = exp2f(m_run - mnew);
            m_run = mnew;
            l_run *= scale;
#pragma unroll
            for (int jn = 0; jn < 16; ++jn) {
                float sc = __shfl(scale, (jn & 3) + 8 * (jn >> 2) + 4 * hi, 64);
                accO[0][jn] *= sc;
                accO[1][jn] *= sc;
            }
        }
#pragma unroll
        for (int i = 0; i < 32; ++i) s[i] = exp2f(s[i] - m_run);
        // tree sum
        float u8[8];
#pragma unroll
        for (int i = 0; i < 8; ++i)
            u8[i] = (s[i] + s[i + 8]) + (s[i + 16] + s[i + 24]);
#pragma unroll
        for (int i = 0; i < 4; ++i) u8[i] += u8[i + 4];
        float psum = (u8[0] + u8[1]) + (u8[2] + u8[3]);
        psum += __shfl_xor(psum, 32, 64);               // cross-half
        l_run += psum;

        // V fragments: 1KB contiguous per load (fragment-major layout)
        v8s vf0[4], vf1[4];
#pragma unroll
        for (int ks = 0; ks < 4; ++ks) {
            vf0[ks] = *(const v8s*)(Vt + ks * 1024 + lq * 16 + hi * 8);
            vf1[ks] = *(const v8s*)(Vt + ks * 1024 + (lq + 32) * 16 + hi * 8);
        }

        // P -> PV A-operand in registers (cvt_pk + permlane32_swap; SSA-distinct)
        v8s PA[4];
#pragma unroll
        for (int t = 0; t < 2; ++t)
#pragma unroll
            for (int sf = 0; sf < 2; ++sf) {
                int base = t * 16 + sf * 8;
                unsigned x0 = cvtpk(s[base + 0], s[base + 1]);
                unsigned x1 = cvtpk(s[base + 2], s[base + 3]);
                unsigned y0 = cvtpk(s[base + 4], s[base + 5]);
                unsigned y1 = cvtpk(s[base + 6], s[base + 7]);
                asm volatile("v_permlane32_swap_b32 %0, %1" : "+v"(x0), "+v"(y0));
                asm volatile("v_permlane32_swap_b32 %0, %1" : "+v"(x1), "+v"(y1));
                v4u wv; wv[0] = x0; wv[1] = x1; wv[2] = y0; wv[3] = y1;
                union { v4u u; v8s s8; } cvt; cvt.u = wv;
                PA[t * 2 + sf] = cvt.s8;
            }

        __builtin_amdgcn_s_setprio(1);
#pragma unroll
        for (int ks = 0; ks < 4; ++ks) {
            accO[0] = MFMA32(PA[ks], vf0[ks], accO[0]);
            accO[1] = MFMA32(PA[ks], vf1[ks], accO[1]);
        }
        __builtin_amdgcn_s_setprio(0);
    };

    // main causal loop — no barriers, compiler-pipelined
    for (int kt = 0; kt < NT; ++kt)
        tile(kt, kt * 64 + 63 > qmin);

    // Rescue (per-wave): rows whose causal-valid keys are ALL masked tie
    // with future keys at exactly -CMASK (fp32 reference semantics).
    int kt = NT;
    while (kt < 32 && __any(m_run < -1e11f)) {
        tile(kt, true);
        ++kt;
    }

    // epilogue: write Ob at COMPACTED row (dense for out_gemm_c)
    float inv = 1.0f / l_run;
#pragma unroll
    for (int jn = 0; jn < 16; ++jn) {
        int rowq = (jn & 3) + 8 * (jn >> 2) + 4 * hi;
        float iv = __shfl(inv, rowq, 64);
        int jrow = cy + rowq;                          // compacted row
        if (jrow < nqv) {
            size_t base = (size_t)(b * S_LEN + jrow) * 1024 + hd * 64 + lq;
            O[base]      = f2bf(accO[0][jn] * iv);
            O[base + 32] = f2bf(accO[1][jn] * iv);
        }
    }
}

// ---------------- output projection, q-compacted (scatter + bias) ----------
// Same XCD map + dbuf/counted-vmcnt pipeline (frozen from R19).
__global__ __launch_bounds__(256)
void out_gemm_c(const short* __restrict__ A, const short* __restrict__ BT,
                const float* __restrict__ bias, const int* __restrict__ idx,
                const int* __restrict__ nq, float* __restrict__ out) {
    __shared__ short As[2][128 * 64];
    __shared__ short Bs[2][128 * 64];
    const int tid = threadIdx.x;
    const int l = tid & 63, w = tid >> 6;
    const int g = l >> 4, ql = l & 15;
    const int bid = blockIdx.x;
    const int y = (bid & 7) + 8 * (bid >> 6);   // M-tile (XCD-pinned)
    if (y >= 36) return;
    const int n0 = ((bid >> 3) & 7) * 128;      // N-tile (cycles fastest)
    const int b = y / 9;
    const int m0c = (y % 9) * 128;
    const int nqv = nq[b];
    if (m0c >= nqv) return;
    const int* idxb = idx + b * S_LEN;
    const int wr = w >> 1, wc = w & 1;
    const int c8 = (((l & 7) ^ (l >> 3))) * 8;  // pre-swizzled source chunk

    v4f acc[4][4] = {};

    auto stage = [&](int kt, int buf) {
        const int kk = kt * 64;
#pragma unroll
        for (int i = 0; i < 4; ++i) {
            int ci = i * 256 + tid;
            int row = ci >> 3;
            async16((char*)As[buf] + (size_t)(i * 256 + w * 64) * 16,
                    A + (size_t)(b * S_LEN + m0c + row) * 1024 + kk + c8);
            async16((char*)Bs[buf] + (size_t)(i * 256 + w * 64) * 16,
                    BT + (size_t)(n0 + row) * 1024 + kk + c8);
        }
    };

    stage(0, 0);
    for (int kt = 0; kt < 16; ++kt) {
        __builtin_amdgcn_s_barrier();         // B1: buf (kt+1)&1 free to write
        __builtin_amdgcn_sched_barrier(0);
        if (kt + 1 < 16) {
            stage(kt + 1, (kt + 1) & 1);
            asm volatile("s_waitcnt vmcnt(8)" ::: "memory");  // kt's loads done
        } else {
            asm volatile("s_waitcnt vmcnt(0)" ::: "memory");
        }
        __builtin_amdgcn_sched_barrier(0);
        __builtin_amdgcn_s_barrier();         // B2: buf kt&1 staged (all waves)
        __builtin_amdgcn_sched_barrier(0);    // rule #18: no ds_read hoisting
        const short* Ab = As[kt & 1];
        const short* Bb = Bs[kt & 1];
#pragma unroll
        for (int ks = 0; ks < 2; ++ks) {
            v8s af[4], bfr[4];
#pragma unroll
            for (int mt = 0; mt < 4; ++mt)
                af[mt] = *(const v8s*)((char*)Ab +
                          swz(wr * 64 + mt * 16 + ql, ks * 64 + g * 16));
#pragma unroll
            for (int nt = 0; nt < 4; ++nt)
                bfr[nt] = *(const v8s*)((char*)Bb +
                          swz(wc * 64 + nt * 16 + ql, ks * 64 + g * 16));
#pragma unroll
            for (int mt = 0; mt < 4; ++mt)
#pragma unroll
                for (int nt = 0; nt < 4; ++nt)
                    acc[mt][nt] = MFMA16(af[mt], bfr[nt], acc[mt][nt]);
        }
    }

#pragma unroll
    for (int nt = 0; nt < 4; ++nt) {
        int col = n0 + wc * 64 + nt * 16 + ql;
        float bval = bias[col];
#pragma unroll
        for (int mt = 0; mt < 4; ++mt) {
#pragma unroll
            for (int r = 0; r < 4; ++r) {
                int jc = m0c + wr * 64 + mt * 16 + g * 4 + r;   // compacted row
                if (jc < nqv) {
                    int orig = idxb[jc];
                    out[(size_t)(b * S_LEN + orig) * 1024 + col] =
                        acc[mt][nt][r] + bval;
                }
            }
        }
    }
}

extern "C" void kernel_launch(void* const* d_in, const int* in_sizes, int n_in,
                              void* d_out, int out_size, void* d_ws, size_t ws_size,
                              hipStream_t stream) {
    (void)in_sizes; (void)n_in; (void)out_size; (void)ws_size;
    const float* q  = (const float*)d_in[0];
    const float* k  = (const float*)d_in[1];
    const float* v  = (const float*)d_in[2];
    const int* qmask = (const int*)d_in[3];
    const int* vmask = (const int*)d_in[4];
    const float* Wq = (const float*)d_in[5];
    const float* bq = (const float*)d_in[6];
    const float* Wk = (const float*)d_in[7];
    const float* bk = (const float*)d_in[8];
    const float* Wv = (const float*)d_in[9];
    const float* bv = (const float*)d_in[10];
    const float* Wo = (const float*)d_in[11];
    const float* bo = (const float*)d_in[12];
    float* out = (float*)d_out;

    char* ws = (char*)d_ws;
    const size_t MB = 1024 * 1024;
    short* WTq = (short*)(ws + 48 * MB);
    short* WTk = (short*)(ws + 50 * MB);
    short* WTv = (short*)(ws + 52 * MB);
    short* WTo = (short*)(ws + 54 * MB);
    short* QW  = (short*)(ws + 56 * MB);
    short* KF  = (short*)(ws + 72 * MB);
    short* VFb = (short*)(ws + 88 * MB);
    short* Ob  = (short*)(ws + 104 * MB);
    short* penC = (short*)(ws + 120 * MB);
    int* idxB  = (int*)(ws + 121 * MB);
    int* nqB   = (int*)(ws + 122 * MB);

    transpose_all<<<dim3(32, 32, 4), 256, 0, stream>>>(Wq, Wk, Wv, Wo,
                                                       WTq, WTk, WTv, WTo);
    build_pen<<<32, 256, 0, stream>>>(vmask, penC);
    compact_qmask<<<NB, 256, 0, stream>>>(qmask, idxB, nqB);
    zero_out<<<2048, 256, 0, stream>>>(out);

    proj_all<<<dim3(512, 1, 3), 256, 0, stream>>>(k, v, q, WTk, WTv, WTq,
                                                  bk, bv, bq, idxB, nqB,
                                                  KF, VFb, QW);
    attn_kernel<<<dim3(64, 64), 64, 0, stream>>>(QW, KF, VFb, penC, idxB, nqB, Ob);
    out_gemm_c<<<320, 256, 0, stream>>>(Ob, WTo, bo, idxB, nqB, out);
}

// Round 21
// 219.229 us; speedup vs baseline: 1.0326x; 1.0326x over previous
//
#include <hip/hip_runtime.h>
#include <hip/hip_bf16.h>

// ---- types ----
typedef __attribute__((ext_vector_type(8))) short v8s;   // 8 x bf16
typedef __attribute__((ext_vector_type(4))) float v4f;
typedef __attribute__((ext_vector_type(16))) float v16f; // 32x32 MFMA C/D
typedef __attribute__((ext_vector_type(4))) unsigned v4u;

#define S_LEN 2048
#define NB 4
#define NH 16
#define LOG2E 1.4426950408889634f
// Mask constant: 1.3125 * 2^40 — EXACTLY representable in bf16 AND fp32.
#define CMASK 1443109011456.0f
#define DEFER_THR 11.55f                // ~8 * log2(e)  (T13)

__device__ __forceinline__ short f2bf(float f) {
    __hip_bfloat16 h = __float2bfloat16(f);
    union { __hip_bfloat16 h; short s; } u; u.h = h; return u.s;
}

__device__ __forceinline__ unsigned cvtpk(float lo, float hi) {
    unsigned r;
    asm("v_cvt_pk_bf16_f32 %0, %1, %2" : "=v"(r) : "v"(lo), "v"(hi));
    return r;
}

// XOR swizzle for [R][128B] LDS tiles (read side); write side realized by
// pre-swizzling the gload_lds SOURCE chunk (rule #21, R8-verified involution).
__device__ __forceinline__ int swz(int row, int col) {
    return (row * 128 + col) ^ ((row & 7) << 4);
}

__device__ __forceinline__ void async16(void* lds, const void* g) {
    __builtin_amdgcn_global_load_lds(
        (const __attribute__((address_space(1))) unsigned int*)g,
        (__attribute__((address_space(3))) unsigned int*)lds, 16, 0, 0);
}

#define MFMA16(a, b, c) __builtin_amdgcn_mfma_f32_16x16x32_bf16((a), (b), (c), 0, 0, 0)
#define MFMA32(a, b, c) __builtin_amdgcn_mfma_f32_32x32x16_bf16((a), (b), (c), 0, 0, 0)

// ------- fused convert fp32->bf16 (q,k,v) + zero-fill of out (y=3) ---------
__global__ __launch_bounds__(256) void convert_all(const float* __restrict__ q,
                                                   const float* __restrict__ k,
                                                   const float* __restrict__ v,
                                                   short* __restrict__ Xq,
                                                   short* __restrict__ Xk,
                                                   short* __restrict__ Xv,
                                                   float* __restrict__ outz) {
    if (blockIdx.y == 3) {                    // zero-fill out (dead rows = 0)
        size_t i = ((size_t)blockIdx.x * 256 + threadIdx.x) * 8;
        float4 z4 = {0.f, 0.f, 0.f, 0.f};
        *(float4*)(outz + i) = z4;
        *(float4*)(outz + i + 4) = z4;
        return;
    }
    const float* in = (blockIdx.y == 0) ? q : (blockIdx.y == 1) ? k : v;
    short* out = (blockIdx.y == 0) ? Xq : (blockIdx.y == 1) ? Xk : Xv;
    size_t i = ((size_t)blockIdx.x * 256 + threadIdx.x) * 8;
    float4 a = *(const float4*)(in + i);
    float4 b = *(const float4*)(in + i + 4);
    v8s o;
    o[0] = f2bf(a.x); o[1] = f2bf(a.y); o[2] = f2bf(a.z); o[3] = f2bf(a.w);
    o[4] = f2bf(b.x); o[5] = f2bf(b.y); o[6] = f2bf(b.z); o[7] = f2bf(b.w);
    *(v8s*)(out + i) = o;
}

// ---------------- penalty column: pen[b][s] = vm ? 0 : -CMASK (bf16) -------
__global__ __launch_bounds__(256) void build_pen(const int* __restrict__ vm,
                                                 short* __restrict__ penC) {
    int i = blockIdx.x * 256 + threadIdx.x;   // 8192 total
    penC[i] = vm[i] ? (short)0 : f2bf(-CMASK);
}

// ------------- q_mask compaction: idx[b][j] = j-th live row, nq[b] ---------
__global__ __launch_bounds__(256) void compact_qmask(const int* __restrict__ qm,
                                                     int* __restrict__ idx,
                                                     int* __restrict__ nq) {
    const int b = blockIdx.x;
    const int* m = qm + b * S_LEN;
    int* ib = idx + b * S_LEN;
    __shared__ int cnt[256];
    const int t = threadIdx.x;
    int loc[8], c = 0;
#pragma unroll
    for (int i = 0; i < 8; ++i) { int s = t * 8 + i; if (m[s]) loc[c++] = s; }
    cnt[t] = c;
    __syncthreads();
    for (int d = 1; d < 256; d <<= 1) {       // Hillis-Steele inclusive scan
        int v = (t >= d) ? cnt[t - d] : 0;
        __syncthreads();
        cnt[t] += v;
        __syncthreads();
    }
    int off = cnt[t] - c;                     // exclusive prefix
    for (int i = 0; i < c; ++i) ib[off + i] = loc[i];
    if (t == 255) nq[b] = cnt[255];
}

// ---------------- fused W[K][N] fp32 -> WT[N][K] bf16 (4 weights) ----------
__global__ __launch_bounds__(256) void transpose_all(const float* __restrict__ Wq,
                                                     const float* __restrict__ Wk,
                                                     const float* __restrict__ Wv,
                                                     const float* __restrict__ Wo,
                                                     short* __restrict__ WTq,
                                                     short* __restrict__ WTk,
                                                     short* __restrict__ WTv,
                                                     short* __restrict__ WTo) {
    const int z = blockIdx.z;
    const float* W = (z == 0) ? Wq : (z == 1) ? Wk : (z == 2) ? Wv : Wo;
    short* WT = (z == 0) ? WTq : (z == 1) ? WTk : (z == 2) ? WTv : WTo;
    __shared__ float tile[32][33];
    int k0 = blockIdx.x * 32, n0 = blockIdx.y * 32;
    int tx = threadIdx.x & 31, ty = threadIdx.x >> 5;  // ty 0..7
#pragma unroll
    for (int i = 0; i < 4; ++i)
        tile[ty + i * 8][tx] = W[(size_t)(k0 + ty + i * 8) * 1024 + n0 + tx];
    __syncthreads();
#pragma unroll
    for (int i = 0; i < 4; ++i)
        WT[(size_t)(n0 + ty + i * 8) * 1024 + k0 + tx] = f2bf(tile[tx][ty + i * 8]);
}

// ---------------- unified projection GEMM: z=0 K, z=1 V, z=2 Q-compacted ---
// XCD-aware bijective mapping (T1) + LDS XOR-swizzle (G4), R16-verified;
// fragment-major K/V output (R18-verified); double-buffered LDS + counted
// vmcnt (R19-verified). R20's fused fp32 convert REVERTED (regression:
// fp32 A reads doubled HBM bytes and the cvt+ds_write chain joined the
// critical path; separate convert's bf16 output is L3-resident here).
__global__ __launch_bounds__(256)
void proj_all(const short* __restrict__ Xk, const short* __restrict__ Xv,
              const short* __restrict__ Xq,
              const short* __restrict__ WTk, const short* __restrict__ WTv,
              const short* __restrict__ WTq,
              const float* __restrict__ bk, const float* __restrict__ bv,
              const float* __restrict__ bq,
              const int* __restrict__ idx, const int* __restrict__ nq,
              short* __restrict__ KF, short* __restrict__ VF,
              short* __restrict__ QW) {
    __shared__ short As[2][128 * 64];
    __shared__ short Bs[2][128 * 64];
    const int tid = threadIdx.x;
    const int l = tid & 63, w = tid >> 6;
    const int g = l >> 4, ql = l & 15;
    const int z = blockIdx.z;
    const int bid = blockIdx.x;
    const int y = (bid & 7) + 8 * (bid >> 6);   // M-tile (XCD-pinned)
    const int n0 = ((bid >> 3) & 7) * 128;      // N-tile (cycles fastest)
    const int wr = w >> 1, wc = w & 1;

    int b = 0, m0 = y * 128, m0c = 0, nqv = 0;
    const int* idxb = nullptr;
    if (z == 2) {
        if (y >= 36) return;
        b = y / 9; m0c = (y % 9) * 128;
        nqv = nq[b];
        if (m0c >= nqv) return;
        idxb = idx + b * S_LEN;
    }
    const short* A  = (z == 0) ? Xk : (z == 1) ? Xv : Xq;
    const short* BT = (z == 0) ? WTk : (z == 1) ? WTv : WTq;
    const float* bias = (z == 0) ? bk : (z == 1) ? bv : bq;

    // per-thread A-row (gathered for Q slice; linear otherwise)
    int arow[4];
#pragma unroll
    for (int i = 0; i < 4; ++i) {
        int row = (i * 256 + tid) >> 3;
        if (z == 2) {
            int jc = m0c + row;
            arow[i] = b * S_LEN + idxb[(jc < nqv) ? jc : (nqv - 1)];
        } else {
            arow[i] = m0 + row;
        }
    }
    // pre-swizzled source chunk (rule #21)
    const int c8 = (((l & 7) ^ (l >> 3))) * 8;

    v4f acc[4][4] = {};

    auto stage = [&](int kt, int buf) {
        const int kk = kt * 64;
#pragma unroll
        for (int i = 0; i < 4; ++i) {
            int ci = i * 256 + tid;
            async16((char*)As[buf] + (size_t)(i * 256 + w * 64) * 16,
                    A + (size_t)arow[i] * 1024 + kk + c8);
            async16((char*)Bs[buf] + (size_t)(i * 256 + w * 64) * 16,
                    BT + (size_t)(n0 + (ci >> 3)) * 1024 + kk + c8);
        }
    };

    stage(0, 0);
    for (int kt = 0; kt < 16; ++kt) {
        __builtin_amdgcn_s_barrier();         // B1: buf (kt+1)&1 free to write
        __builtin_amdgcn_sched_barrier(0);
        if (kt + 1 < 16) {
            stage(kt + 1, (kt + 1) & 1);
            asm volatile("s_waitcnt vmcnt(8)" ::: "memory");  // kt's loads done
        } else {
            asm volatile("s_waitcnt vmcnt(0)" ::: "memory");
        }
        __builtin_amdgcn_sched_barrier(0);
        __builtin_amdgcn_s_barrier();         // B2: buf kt&1 staged (all waves)
        __builtin_amdgcn_sched_barrier(0);    // rule #18: no ds_read hoisting
        const short* Ab = As[kt & 1];
        const short* Bb = Bs[kt & 1];
#pragma unroll
        for (int ks = 0; ks < 2; ++ks) {
            v8s af[4], bfr[4];
#pragma unroll
            for (int mt = 0; mt < 4; ++mt)
                af[mt] = *(const v8s*)((char*)Ab +
                          swz(wr * 64 + mt * 16 + ql, ks * 64 + g * 16));
#pragma unroll
            for (int nt = 0; nt < 4; ++nt)
                bfr[nt] = *(const v8s*)((char*)Bb +
                          swz(wc * 64 + nt * 16 + ql, ks * 64 + g * 16));
#pragma unroll
            for (int mt = 0; mt < 4; ++mt)
#pragma unroll
                for (int nt = 0; nt < 4; ++nt)
                    acc[mt][nt] = MFMA16(af[mt], bfr[nt], acc[mt][nt]);
        }
    }

#pragma unroll
    for (int nt = 0; nt < 4; ++nt) {
        int col = n0 + wc * 64 + nt * 16 + ql;
        float bval = bias[col];
        int hh = col >> 6, dd = col & 63;
#pragma unroll
        for (int mt = 0; mt < 4; ++mt) {
#pragma unroll
            for (int r = 0; r < 4; ++r) {
                int lrow = wr * 64 + mt * 16 + g * 4 + r;
                float vv = acc[mt][nt][r] + bval;
                if (z == 0) {
                    int gm = m0 + lrow;
                    int bb = gm >> 11, ss = gm & 2047;
                    // K fragment layout: [bh][kt][ks][row][hi][8]
                    size_t base = (size_t)(bb * NH + hh) * 131072
                                + (size_t)(ss >> 6) * 4096
                                + (dd >> 4) * 1024 + (ss & 63) * 16
                                + ((dd >> 3) & 1) * 8 + (dd & 7);
                    KF[base] = f2bf(vv);
                } else if (z == 1) {
                    int gm = m0 + lrow;
                    int bb = gm >> 11, ss = gm & 2047;
                    // V fragment layout: [bh][kt][ks][d][hi][8] (kp-split)
                    int wkp = ss & 63;
                    size_t base = (size_t)(bb * NH + hh) * 131072
                                + (size_t)(ss >> 6) * 4096
                                + (wkp >> 4) * 1024 + dd * 16
                                + ((wkp >> 3) & 1) * 8 + (wkp & 7);
                    VF[base] = f2bf(vv);
                } else {
                    int jc = m0c + lrow;                 // compacted row
                    vv *= 0.125f * LOG2E;
                    QW[((size_t)(b * NH + hh) * S_LEN + jc) * 64 + dd] = f2bf(vv);
                }
            }
        }
    }
}

// ---------------- flash attention: streaming, fragment-major K/V -----------
// (frozen from R18: 1-wave blocks, no LDS, no barriers, 1KB-contiguous
// fragment loads)
__global__ __launch_bounds__(64)
void attn_kernel(const short* __restrict__ QW, const short* __restrict__ KF,
                 const short* __restrict__ VF, const short* __restrict__ penC,
                 const int* __restrict__ idx, const int* __restrict__ nq,
                 short* __restrict__ O) {
    const int l = threadIdx.x;                // 1 wave
    const int lq = l & 31, hi = l >> 5;
    const int bh = blockIdx.x;
    const int chunk = 63 - (int)blockIdx.y;   // heavy chunks dispatch first
    const int b = bh >> 4, hd = bh & 15;

    const int nqv = nq[b];
    const int cy = chunk * 32;                // compacted base row (32/wave)
    if (cy >= nqv) return;                    // dead chunk retires instantly

    const short* Qp = QW + (size_t)bh * S_LEN * 64;
    const short* Kp = KF + (size_t)bh * 131072;
    const short* Vp = VF + (size_t)bh * 131072;
    const short* pp = penC + b * S_LEN;
    const int* idxb = idx + b * S_LEN;

    const int j = cy + lq;
    const int jj = (j < nqv) ? j : (nqv - 1);
    const int q_glob = idxb[jj];
    const int qmin = __builtin_amdgcn_readfirstlane(q_glob);

    int lastj = cy + 31; if (lastj > nqv - 1) lastj = nqv - 1;
    const int NT = (idxb[lastj] >> 6) + 1;

    // Q fragments from COMPACTED QW
    v8s qf[4];
#pragma unroll
    for (int ks = 0; ks < 4; ++ks)
        qf[ks] = *(const v8s*)(Qp + (size_t)jj * 64 + ks * 16 + hi * 8);
    v8s qf4 = {};
    qf4[0] = hi ? (short)0 : (short)0x3F80;   // bf16(1.0) at virtual k=64

    v16f accO[2] = {};
    float m_run = -INFINITY, l_run = 0.f;

    auto tile = [&](int kt, bool causal) {
        const int k0 = kt * 64;
        const short* Kt = Kp + (size_t)kt * 4096;
        const short* Vt = Vp + (size_t)kt * 4096;
        short p0 = pp[k0 + lq], p1 = pp[k0 + lq + 32];

        // K fragments: 1KB contiguous per load (fragment-major layout)
        v8s kf0[4], kf1[4];
#pragma unroll
        for (int ks = 0; ks < 4; ++ks) {
            kf0[ks] = *(const v8s*)(Kt + ks * 1024 + lq * 16 + hi * 8);
            kf1[ks] = *(const v8s*)(Kt + ks * 1024 + (lq + 32) * 16 + hi * 8);
        }
        v16f acc0 = {}, acc1 = {};
        __builtin_amdgcn_s_setprio(1);
#pragma unroll
        for (int ks = 0; ks < 4; ++ks) {
            acc0 = MFMA32(kf0[ks], qf[ks], acc0);
            acc1 = MFMA32(kf1[ks], qf[ks], acc1);
        }
        // 5th slice: v_mask penalty column (hi=0 lanes carry pen at k=64)
        v8s k4a = {}, k4b = {};
        k4a[0] = hi ? (short)0 : p0;
        k4b[0] = hi ? (short)0 : p1;
        acc0 = MFMA32(k4a, qf4, acc0);
        acc1 = MFMA32(k4b, qf4, acc1);
        __builtin_amdgcn_s_setprio(0);

        float s[32];
#pragma unroll
        for (int jn = 0; jn < 16; ++jn) { s[jn] = acc0[jn]; s[16 + jn] = acc1[jn]; }
        if (causal) {
#pragma unroll
            for (int t = 0; t < 2; ++t)
#pragma unroll
                for (int jn = 0; jn < 16; ++jn) {
                    int kp = k0 + t * 32 + (jn & 3) + 8 * (jn >> 2) + 4 * hi;
                    if (kp > q_glob) s[t * 16 + jn] -= CMASK;
                }
        }
        // tree max (depth 5)
        float t8[8];
#pragma unroll
        for (int i = 0; i < 8; ++i)
            t8[i] = fmaxf(fmaxf(s[i], s[i + 8]), fmaxf(s[i + 16], s[i + 24]));
#pragma unroll
        for (int i = 0; i < 4; ++i) t8[i] = fmaxf(t8[i], t8[i + 4]);
        float tmax = fmaxf(fmaxf(t8[0], t8[1]), fmaxf(t8[2], t8[3]));
        tmax = fmaxf(tmax, __shfl_xor(tmax, 32, 64));   // cross-half

        // T13 defer-max
        if (__any(tmax > m_run + DEFER_THR)) {
            float mnew = fmaxf(m_run, tmax);
            float scale = exp2f(m_run - mnew);
            m_run = mnew;
            l_run *= scale;
#pragma unroll
            for (int jn = 0; jn < 16; ++jn) {
                float sc = __shfl(scale, (jn & 3) + 8 * (jn >> 2) + 4 * hi, 64);
                accO[0][jn] *= sc;
                accO[1][jn] *= sc;
            }
        }
#pragma unroll
        for (int i = 0; i < 32; ++i) s[i] = exp2f(s[i] - m_run);
        // tree sum
        float u8[8];
#pragma unroll
        for (int i = 0; i < 8; ++i)
            u8[i] = (s[i] + s[i + 8]) + (s[i + 16] + s[i + 24]);
#pragma unroll
        for (int i = 0; i < 4; ++i) u8[i] += u8[i + 4];
        float psum = (u8[0] + u8[1]) + (u8[2] + u8[3]);
        psum += __shfl_xor(psum, 32, 64);               // cross-half
        l_run += psum;

        // V fragments: 1KB contiguous per load (fragment-major layout)
        v8s vf0[4], vf1[4];
#pragma unroll
        for (int ks = 0; ks < 4; ++ks) {
            vf0[ks] = *(const v8s*)(Vt + ks * 1024 + lq * 16 + hi * 8);
            vf1[ks] = *(const v8s*)(Vt + ks * 1024 + (lq + 32) * 16 + hi * 8);
        }

        // P -> PV A-operand in registers (cvt_pk + permlane32_swap; SSA-distinct)
        v8s PA[4];
#pragma unroll
        for (int t = 0; t < 2; ++t)
#pragma unroll
            for (int sf = 0; sf < 2; ++sf) {
                int base = t * 16 + sf * 8;
                unsigned x0 = cvtpk(s[base + 0], s[base + 1]);
                unsigned x1 = cvtpk(s[base + 2], s[base + 3]);
                unsigned y0 = cvtpk(s[base + 4], s[base + 5]);
                unsigned y1 = cvtpk(s[base + 6], s[base + 7]);
                asm volatile("v_permlane32_swap_b32 %0, %1" : "+v"(x0), "+v"(y0));
                asm volatile("v_permlane32_swap_b32 %0, %1" : "+v"(x1), "+v"(y1));
                v4u wv; wv[0] = x0; wv[1] = x1; wv[2] = y0; wv[3] = y1;
                union { v4u u; v8s s8; } cvt; cvt.u = wv;
                PA[t * 2 + sf] = cvt.s8;
            }

        __builtin_amdgcn_s_setprio(1);
#pragma unroll
        for (int ks = 0; ks < 4; ++ks) {
            accO[0] = MFMA32(PA[ks], vf0[ks], accO[0]);
            accO[1] = MFMA32(PA[ks], vf1[ks], accO[1]);
        }
        __builtin_amdgcn_s_setprio(0);
    };

    // main causal loop — no barriers, compiler-pipelined
    for (int kt = 0; kt < NT; ++kt)
        tile(kt, kt * 64 + 63 > qmin);

    // Rescue (per-wave): rows whose causal-valid keys are ALL masked tie
    // with future keys at exactly -CMASK (fp32 reference semantics).
    int kt = NT;
    while (kt < 32 && __any(m_run < -1e11f)) {
        tile(kt, true);
        ++kt;
    }

    // epilogue: write Ob at COMPACTED row (dense for out_gemm_c)
    float inv = 1.0f / l_run;
#pragma unroll
    for (int jn = 0; jn < 16; ++jn) {
        int rowq = (jn & 3) + 8 * (jn >> 2) + 4 * hi;
        float iv = __shfl(inv, rowq, 64);
        int jrow = cy + rowq;                          // compacted row
        if (jrow < nqv) {
            size_t base = (size_t)(b * S_LEN + jrow) * 1024 + hd * 64 + lq;
            O[base]      = f2bf(accO[0][jn] * iv);
            O[base + 32] = f2bf(accO[1][jn] * iv);
        }
    }
}

// ---------------- output projection, q-compacted (scatter + bias) ----------
// Same XCD map + dbuf/counted-vmcnt pipeline as proj_all.
__global__ __launch_bounds__(256)
void out_gemm_c(const short* __restrict__ A, const short* __restrict__ BT,
                const float* __restrict__ bias, const int* __restrict__ idx,
                const int* __restrict__ nq, float* __restrict__ out) {
    __shared__ short As[2][128 * 64];
    __shared__ short Bs[2][128 * 64];
    const int tid = threadIdx.x;
    const int l = tid & 63, w = tid >> 6;
    const int g = l >> 4, ql = l & 15;
    const int bid = blockIdx.x;
    const int y = (bid & 7) + 8 * (bid >> 6);   // M-tile (XCD-pinned)
    if (y >= 36) return;
    const int n0 = ((bid >> 3) & 7) * 128;      // N-tile (cycles fastest)
    const int b = y / 9;
    const int m0c = (y % 9) * 128;
    const int nqv = nq[b];
    if (m0c >= nqv) return;
    const int* idxb = idx + b * S_LEN;
    const int wr = w >> 1, wc = w & 1;
    const int c8 = (((l & 7) ^ (l >> 3))) * 8;  // pre-swizzled source chunk

    v4f acc[4][4] = {};

    auto stage = [&](int kt, int buf) {
        const int kk = kt * 64;
#pragma unroll
        for (int i = 0; i < 4; ++i) {
            int ci = i * 256 + tid;
            int row = ci >> 3;
            async16((char*)As[buf] + (size_t)(i * 256 + w * 64) * 16,
                    A + (size_t)(b * S_LEN + m0c + row) * 1024 + kk + c8);
            async16((char*)Bs[buf] + (size_t)(i * 256 + w * 64) * 16,
                    BT + (size_t)(n0 + row) * 1024 + kk + c8);
        }
    };

    stage(0, 0);
    for (int kt = 0; kt < 16; ++kt) {
        __builtin_amdgcn_s_barrier();         // B1: buf (kt+1)&1 free to write
        __builtin_amdgcn_sched_barrier(0);
        if (kt + 1 < 16) {
            stage(kt + 1, (kt + 1) & 1);
            asm volatile("s_waitcnt vmcnt(8)" ::: "memory");  // kt's loads done
        } else {
            asm volatile("s_waitcnt vmcnt(0)" ::: "memory");
        }
        __builtin_amdgcn_sched_barrier(0);
        __builtin_amdgcn_s_barrier();         // B2: buf kt&1 staged (all waves)
        __builtin_amdgcn_sched_barrier(0);    // rule #18: no ds_read hoisting
        const short* Ab = As[kt & 1];
        const short* Bb = Bs[kt & 1];
#pragma unroll
        for (int ks = 0; ks < 2; ++ks) {
            v8s af[4], bfr[4];
#pragma unroll
            for (int mt = 0; mt < 4; ++mt)
                af[mt] = *(const v8s*)((char*)Ab +
                          swz(wr * 64 + mt * 16 + ql, ks * 64 + g * 16));
#pragma unroll
            for (int nt = 0; nt < 4; ++nt)
                bfr[nt] = *(const v8s*)((char*)Bb +
                          swz(wc * 64 + nt * 16 + ql, ks * 64 + g * 16));
#pragma unroll
            for (int mt = 0; mt < 4; ++mt)
#pragma unroll
                for (int nt = 0; nt < 4; ++nt)
                    acc[mt][nt] = MFMA16(af[mt], bfr[nt], acc[mt][nt]);
        }
    }

#pragma unroll
    for (int nt = 0; nt < 4; ++nt) {
        int col = n0 + wc * 64 + nt * 16 + ql;
        float bval = bias[col];
#pragma unroll
        for (int mt = 0; mt < 4; ++mt) {
#pragma unroll
            for (int r = 0; r < 4; ++r) {
                int jc = m0c + wr * 64 + mt * 16 + g * 4 + r;   // compacted row
                if (jc < nqv) {
                    int orig = idxb[jc];
                    out[(size_t)(b * S_LEN + orig) * 1024 + col] =
                        acc[mt][nt][r] + bval;
                }
            }
        }
    }
}

extern "C" void kernel_launch(void* const* d_in, const int* in_sizes, int n_in,
                              void* d_out, int out_size, void* d_ws, size_t ws_size,
                              hipStream_t stream) {
    (void)in_sizes; (void)n_in; (void)out_size; (void)ws_size;
    const float* q  = (const float*)d_in[0];
    const float* k  = (const float*)d_in[1];
    const float* v  = (const float*)d_in[2];
    const int* qmask = (const int*)d_in[3];
    const int* vmask = (const int*)d_in[4];
    const float* Wq = (const float*)d_in[5];
    const float* bq = (const float*)d_in[6];
    const float* Wk = (const float*)d_in[7];
    const float* bk = (const float*)d_in[8];
    const float* Wv = (const float*)d_in[9];
    const float* bv = (const float*)d_in[10];
    const float* Wo = (const float*)d_in[11];
    const float* bo = (const float*)d_in[12];
    float* out = (float*)d_out;

    char* ws = (char*)d_ws;
    const size_t MB = 1024 * 1024;
    short* Xq  = (short*)(ws + 0 * MB);
    short* Xk  = (short*)(ws + 16 * MB);
    short* Xv  = (short*)(ws + 32 * MB);
    short* WTq = (short*)(ws + 48 * MB);
    short* WTk = (short*)(ws + 50 * MB);
    short* WTv = (short*)(ws + 52 * MB);
    short* WTo = (short*)(ws + 54 * MB);
    short* QW  = (short*)(ws + 56 * MB);
    short* KF  = (short*)(ws + 72 * MB);
    short* VFb = (short*)(ws + 88 * MB);
    short* Ob  = (short*)(ws + 104 * MB);
    short* penC = (short*)(ws + 120 * MB);
    int* idxB  = (int*)(ws + 121 * MB);
    int* nqB   = (int*)(ws + 122 * MB);

    convert_all<<<dim3(4096, 4), 256, 0, stream>>>(q, k, v, Xq, Xk, Xv, out);
    transpose_all<<<dim3(32, 32, 4), 256, 0, stream>>>(Wq, Wk, Wv, Wo,
                                                       WTq, WTk, WTv, WTo);
    build_pen<<<32, 256, 0, stream>>>(vmask, penC);
    compact_qmask<<<NB, 256, 0, stream>>>(qmask, idxB, nqB);

    proj_all<<<dim3(512, 1, 3), 256, 0, stream>>>(Xk, Xv, Xq, WTk, WTv, WTq,
                                                  bk, bv, bq, idxB, nqB,
                                                  KF, VFb, QW);
    attn_kernel<<<dim3(64, 64), 64, 0, stream>>>(QW, KF, VFb, penC, idxB, nqB, Ob);
    out_gemm_c<<<320, 256, 0, stream>>>(Ob, WTo, bo, idxB, nqB, out);
}

// Round 22
// 211.512 us; speedup vs baseline: 1.0703x; 1.0365x over previous
//
#include <hip/hip_runtime.h>
#include <hip/hip_bf16.h>

// ---- types ----
typedef __attribute__((ext_vector_type(8))) short v8s;   // 8 x bf16
typedef __attribute__((ext_vector_type(4))) float v4f;
typedef __attribute__((ext_vector_type(16))) float v16f; // 32x32 MFMA C/D
typedef __attribute__((ext_vector_type(4))) unsigned v4u;

#define S_LEN 2048
#define NB 4
#define NH 16
#define LOG2E 1.4426950408889634f
// Mask constant: 1.3125 * 2^40 — EXACTLY representable in bf16 AND fp32.
#define CMASK 1443109011456.0f
#define DEFER_THR 11.55f                // ~8 * log2(e)  (T13)

__device__ __forceinline__ short f2bf(float f) {
    __hip_bfloat16 h = __float2bfloat16(f);
    union { __hip_bfloat16 h; short s; } u; u.h = h; return u.s;
}

__device__ __forceinline__ unsigned cvtpk(float lo, float hi) {
    unsigned r;
    asm("v_cvt_pk_bf16_f32 %0, %1, %2" : "=v"(r) : "v"(lo), "v"(hi));
    return r;
}

// XOR swizzle for [R][128B] LDS tiles (read side); write side realized by
// pre-swizzling the gload_lds SOURCE chunk (rule #21, R8-verified involution).
__device__ __forceinline__ int swz(int row, int col) {
    return (row * 128 + col) ^ ((row & 7) << 4);
}

__device__ __forceinline__ void async16(void* lds, const void* g) {
    __builtin_amdgcn_global_load_lds(
        (const __attribute__((address_space(1))) unsigned int*)g,
        (__attribute__((address_space(3))) unsigned int*)lds, 16, 0, 0);
}

#define MFMA16(a, b, c) __builtin_amdgcn_mfma_f32_16x16x32_bf16((a), (b), (c), 0, 0, 0)
#define MFMA32(a, b, c) __builtin_amdgcn_mfma_f32_32x32x16_bf16((a), (b), (c), 0, 0, 0)

// ------- fused convert fp32->bf16 (q,k,v) + zero-fill of out (y=3) ---------
__global__ __launch_bounds__(256) void convert_all(const float* __restrict__ q,
                                                   const float* __restrict__ k,
                                                   const float* __restrict__ v,
                                                   short* __restrict__ Xq,
                                                   short* __restrict__ Xk,
                                                   short* __restrict__ Xv,
                                                   float* __restrict__ outz) {
    if (blockIdx.y == 3) {                    // zero-fill out (dead rows = 0)
        size_t i = ((size_t)blockIdx.x * 256 + threadIdx.x) * 8;
        float4 z4 = {0.f, 0.f, 0.f, 0.f};
        *(float4*)(outz + i) = z4;
        *(float4*)(outz + i + 4) = z4;
        return;
    }
    const float* in = (blockIdx.y == 0) ? q : (blockIdx.y == 1) ? k : v;
    short* out = (blockIdx.y == 0) ? Xq : (blockIdx.y == 1) ? Xk : Xv;
    size_t i = ((size_t)blockIdx.x * 256 + threadIdx.x) * 8;
    float4 a = *(const float4*)(in + i);
    float4 b = *(const float4*)(in + i + 4);
    v8s o;
    o[0] = f2bf(a.x); o[1] = f2bf(a.y); o[2] = f2bf(a.z); o[3] = f2bf(a.w);
    o[4] = f2bf(b.x); o[5] = f2bf(b.y); o[6] = f2bf(b.z); o[7] = f2bf(b.w);
    *(v8s*)(out + i) = o;
}

// ---------------- penalty column: pen[b][s] = vm ? 0 : -CMASK (bf16) -------
__global__ __launch_bounds__(256) void build_pen(const int* __restrict__ vm,
                                                 short* __restrict__ penC) {
    int i = blockIdx.x * 256 + threadIdx.x;   // 8192 total
    penC[i] = vm[i] ? (short)0 : f2bf(-CMASK);
}

// ------------- q_mask compaction: idx[b][j] = j-th live row, nq[b] ---------
__global__ __launch_bounds__(256) void compact_qmask(const int* __restrict__ qm,
                                                     int* __restrict__ idx,
                                                     int* __restrict__ nq) {
    const int b = blockIdx.x;
    const int* m = qm + b * S_LEN;
    int* ib = idx + b * S_LEN;
    __shared__ int cnt[256];
    const int t = threadIdx.x;
    int loc[8], c = 0;
#pragma unroll
    for (int i = 0; i < 8; ++i) { int s = t * 8 + i; if (m[s]) loc[c++] = s; }
    cnt[t] = c;
    __syncthreads();
    for (int d = 1; d < 256; d <<= 1) {       // Hillis-Steele inclusive scan
        int v = (t >= d) ? cnt[t - d] : 0;
        __syncthreads();
        cnt[t] += v;
        __syncthreads();
    }
    int off = cnt[t] - c;                     // exclusive prefix
    for (int i = 0; i < c; ++i) ib[off + i] = loc[i];
    if (t == 255) nq[b] = cnt[255];
}

// ---------------- fused W[K][N] fp32 -> WT[N][K] bf16 (4 weights) ----------
__global__ __launch_bounds__(256) void transpose_all(const float* __restrict__ Wq,
                                                     const float* __restrict__ Wk,
                                                     const float* __restrict__ Wv,
                                                     const float* __restrict__ Wo,
                                                     short* __restrict__ WTq,
                                                     short* __restrict__ WTk,
                                                     short* __restrict__ WTv,
                                                     short* __restrict__ WTo) {
    const int z = blockIdx.z;
    const float* W = (z == 0) ? Wq : (z == 1) ? Wk : (z == 2) ? Wv : Wo;
    short* WT = (z == 0) ? WTq : (z == 1) ? WTk : (z == 2) ? WTv : WTo;
    __shared__ float tile[32][33];
    int k0 = blockIdx.x * 32, n0 = blockIdx.y * 32;
    int tx = threadIdx.x & 31, ty = threadIdx.x >> 5;  // ty 0..7
#pragma unroll
    for (int i = 0; i < 4; ++i)
        tile[ty + i * 8][tx] = W[(size_t)(k0 + ty + i * 8) * 1024 + n0 + tx];
    __syncthreads();
#pragma unroll
    for (int i = 0; i < 4; ++i)
        WT[(size_t)(n0 + ty + i * 8) * 1024 + k0 + tx] = f2bf(tile[tx][ty + i * 8]);
}

// ---------------- unified projection GEMM: z=0 K, z=1 V, z=2 Q-compacted ---
// XCD map (T1) + LDS swizzle (G4) + fragment-major K/V (R18) + dbuf/counted
// vmcnt (R19). NEW (R22): 8-WAVE BLOCKS (512 thr), wave grid 2x4, per-wave
// tile 64x32, acc[4][2]. Same 128^2 tile & 64KB LDS -> still 2 blocks/CU,
// but 16 waves/CU = 4/SIMD (was 2): doubles the latency-hiding TLP that the
// counted-vmcnt pipeline alone couldn't supply (R19-21: Occ 18.6%,
// MfmaUtil 20.5, HBM 13% -> latency-bound). Staging: 2 iters x 512 thr,
// 4 VMEM/thread -> vmcnt(4). The c8 involution is decomposition-invariant
// (chunk col = l&7, row&7 = l>>3 hold for any wave's 64-chunk span).
__global__ __launch_bounds__(512)
void proj_all(const short* __restrict__ Xk, const short* __restrict__ Xv,
              const short* __restrict__ Xq,
              const short* __restrict__ WTk, const short* __restrict__ WTv,
              const short* __restrict__ WTq,
              const float* __restrict__ bk, const float* __restrict__ bv,
              const float* __restrict__ bq,
              const int* __restrict__ idx, const int* __restrict__ nq,
              short* __restrict__ KF, short* __restrict__ VF,
              short* __restrict__ QW) {
    __shared__ short As[2][128 * 64];
    __shared__ short Bs[2][128 * 64];
    const int tid = threadIdx.x;
    const int l = tid & 63, w = tid >> 6;       // w in 0..7
    const int g = l >> 4, ql = l & 15;
    const int z = blockIdx.z;
    const int bid = blockIdx.x;
    const int y = (bid & 7) + 8 * (bid >> 6);   // M-tile (XCD-pinned)
    const int n0 = ((bid >> 3) & 7) * 128;      // N-tile (cycles fastest)
    const int wr = w >> 2, wc = w & 3;          // 2x4 wave grid

    int b = 0, m0 = y * 128, m0c = 0, nqv = 0;
    const int* idxb = nullptr;
    if (z == 2) {
        if (y >= 36) return;
        b = y / 9; m0c = (y % 9) * 128;
        nqv = nq[b];
        if (m0c >= nqv) return;
        idxb = idx + b * S_LEN;
    }
    const short* A  = (z == 0) ? Xk : (z == 1) ? Xv : Xq;
    const short* BT = (z == 0) ? WTk : (z == 1) ? WTv : WTq;
    const float* bias = (z == 0) ? bk : (z == 1) ? bv : bq;

    // per-thread A-row (gathered for Q slice; linear otherwise): 2 per thread
    int arow[2];
#pragma unroll
    for (int i = 0; i < 2; ++i) {
        int row = (i * 512 + tid) >> 3;
        if (z == 2) {
            int jc = m0c + row;
            arow[i] = b * S_LEN + idxb[(jc < nqv) ? jc : (nqv - 1)];
        } else {
            arow[i] = m0 + row;
        }
    }
    // pre-swizzled source chunk (rule #21)
    const int c8 = (((l & 7) ^ (l >> 3))) * 8;

    v4f acc[4][2] = {};

    auto stage = [&](int kt, int buf) {
        const int kk = kt * 64;
#pragma unroll
        for (int i = 0; i < 2; ++i) {
            int ci = i * 512 + tid;
            async16((char*)As[buf] + (size_t)ci * 16,
                    A + (size_t)arow[i] * 1024 + kk + c8);
            async16((char*)Bs[buf] + (size_t)ci * 16,
                    BT + (size_t)(n0 + (ci >> 3)) * 1024 + kk + c8);
        }
    };

    stage(0, 0);
    for (int kt = 0; kt < 16; ++kt) {
        __builtin_amdgcn_s_barrier();         // B1: buf (kt+1)&1 free to write
        __builtin_amdgcn_sched_barrier(0);
        if (kt + 1 < 16) {
            stage(kt + 1, (kt + 1) & 1);
            asm volatile("s_waitcnt vmcnt(4)" ::: "memory");  // kt's loads done
        } else {
            asm volatile("s_waitcnt vmcnt(0)" ::: "memory");
        }
        __builtin_amdgcn_sched_barrier(0);
        __builtin_amdgcn_s_barrier();         // B2: buf kt&1 staged (all waves)
        __builtin_amdgcn_sched_barrier(0);    // rule #18: no ds_read hoisting
        const short* Ab = As[kt & 1];
        const short* Bb = Bs[kt & 1];
#pragma unroll
        for (int ks = 0; ks < 2; ++ks) {
            v8s af[4], bfr[2];
#pragma unroll
            for (int mt = 0; mt < 4; ++mt)
                af[mt] = *(const v8s*)((char*)Ab +
                          swz(wr * 64 + mt * 16 + ql, ks * 64 + g * 16));
#pragma unroll
            for (int nt = 0; nt < 2; ++nt)
                bfr[nt] = *(const v8s*)((char*)Bb +
                          swz(wc * 32 + nt * 16 + ql, ks * 64 + g * 16));
#pragma unroll
            for (int mt = 0; mt < 4; ++mt)
#pragma unroll
                for (int nt = 0; nt < 2; ++nt)
                    acc[mt][nt] = MFMA16(af[mt], bfr[nt], acc[mt][nt]);
        }
    }

#pragma unroll
    for (int nt = 0; nt < 2; ++nt) {
        int col = n0 + wc * 32 + nt * 16 + ql;
        float bval = bias[col];
        int hh = col >> 6, dd = col & 63;
#pragma unroll
        for (int mt = 0; mt < 4; ++mt) {
#pragma unroll
            for (int r = 0; r < 4; ++r) {
                int lrow = wr * 64 + mt * 16 + g * 4 + r;
                float vv = acc[mt][nt][r] + bval;
                if (z == 0) {
                    int gm = m0 + lrow;
                    int bb = gm >> 11, ss = gm & 2047;
                    // K fragment layout: [bh][kt][ks][row][hi][8]
                    size_t base = (size_t)(bb * NH + hh) * 131072
                                + (size_t)(ss >> 6) * 4096
                                + (dd >> 4) * 1024 + (ss & 63) * 16
                                + ((dd >> 3) & 1) * 8 + (dd & 7);
                    KF[base] = f2bf(vv);
                } else if (z == 1) {
                    int gm = m0 + lrow;
                    int bb = gm >> 11, ss = gm & 2047;
                    // V fragment layout: [bh][kt][ks][d][hi][8] (kp-split)
                    int wkp = ss & 63;
                    size_t base = (size_t)(bb * NH + hh) * 131072
                                + (size_t)(ss >> 6) * 4096
                                + (wkp >> 4) * 1024 + dd * 16
                                + ((wkp >> 3) & 1) * 8 + (wkp & 7);
                    VF[base] = f2bf(vv);
                } else {
                    int jc = m0c + lrow;                 // compacted row
                    vv *= 0.125f * LOG2E;
                    QW[((size_t)(b * NH + hh) * S_LEN + jc) * 64 + dd] = f2bf(vv);
                }
            }
        }
    }
}

// ---------------- flash attention: streaming, fragment-major K/V -----------
// (frozen from R18: 1-wave blocks, no LDS, no barriers, 1KB-contiguous
// fragment loads)
__global__ __launch_bounds__(64)
void attn_kernel(const short* __restrict__ QW, const short* __restrict__ KF,
                 const short* __restrict__ VF, const short* __restrict__ penC,
                 const int* __restrict__ idx, const int* __restrict__ nq,
                 short* __restrict__ O) {
    const int l = threadIdx.x;                // 1 wave
    const int lq = l & 31, hi = l >> 5;
    const int bh = blockIdx.x;
    const int chunk = 63 - (int)blockIdx.y;   // heavy chunks dispatch first
    const int b = bh >> 4, hd = bh & 15;

    const int nqv = nq[b];
    const int cy = chunk * 32;                // compacted base row (32/wave)
    if (cy >= nqv) return;                    // dead chunk retires instantly

    const short* Qp = QW + (size_t)bh * S_LEN * 64;
    const short* Kp = KF + (size_t)bh * 131072;
    const short* Vp = VF + (size_t)bh * 131072;
    const short* pp = penC + b * S_LEN;
    const int* idxb = idx + b * S_LEN;

    const int j = cy + lq;
    const int jj = (j < nqv) ? j : (nqv - 1);
    const int q_glob = idxb[jj];
    const int qmin = __builtin_amdgcn_readfirstlane(q_glob);

    int lastj = cy + 31; if (lastj > nqv - 1) lastj = nqv - 1;
    const int NT = (idxb[lastj] >> 6) + 1;

    // Q fragments from COMPACTED QW
    v8s qf[4];
#pragma unroll
    for (int ks = 0; ks < 4; ++ks)
        qf[ks] = *(const v8s*)(Qp + (size_t)jj * 64 + ks * 16 + hi * 8);
    v8s qf4 = {};
    qf4[0] = hi ? (short)0 : (short)0x3F80;   // bf16(1.0) at virtual k=64

    v16f accO[2] = {};
    float m_run = -INFINITY, l_run = 0.f;

    auto tile = [&](int kt, bool causal) {
        const int k0 = kt * 64;
        const short* Kt = Kp + (size_t)kt * 4096;
        const short* Vt = Vp + (size_t)kt * 4096;
        short p0 = pp[k0 + lq], p1 = pp[k0 + lq + 32];

        // K fragments: 1KB contiguous per load (fragment-major layout)
        v8s kf0[4], kf1[4];
#pragma unroll
        for (int ks = 0; ks < 4; ++ks) {
            kf0[ks] = *(const v8s*)(Kt + ks * 1024 + lq * 16 + hi * 8);
            kf1[ks] = *(const v8s*)(Kt + ks * 1024 + (lq + 32) * 16 + hi * 8);
        }
        v16f acc0 = {}, acc1 = {};
        __builtin_amdgcn_s_setprio(1);
#pragma unroll
        for (int ks = 0; ks < 4; ++ks) {
            acc0 = MFMA32(kf0[ks], qf[ks], acc0);
            acc1 = MFMA32(kf1[ks], qf[ks], acc1);
        }
        // 5th slice: v_mask penalty column (hi=0 lanes carry pen at k=64)
        v8s k4a = {}, k4b = {};
        k4a[0] = hi ? (short)0 : p0;
        k4b[0] = hi ? (short)0 : p1;
        acc0 = MFMA32(k4a, qf4, acc0);
        acc1 = MFMA32(k4b, qf4, acc1);
        __builtin_amdgcn_s_setprio(0);

        float s[32];
#pragma unroll
        for (int jn = 0; jn < 16; ++jn) { s[jn] = acc0[jn]; s[16 + jn] = acc1[jn]; }
        if (causal) {
#pragma unroll
            for (int t = 0; t < 2; ++t)
#pragma unroll
                for (int jn = 0; jn < 16; ++jn) {
                    int kp = k0 + t * 32 + (jn & 3) + 8 * (jn >> 2) + 4 * hi;
                    if (kp > q_glob) s[t * 16 + jn] -= CMASK;
                }
        }
        // tree max (depth 5)
        float t8[8];
#pragma unroll
        for (int i = 0; i < 8; ++i)
            t8[i] = fmaxf(fmaxf(s[i], s[i + 8]), fmaxf(s[i + 16], s[i + 24]));
#pragma unroll
        for (int i = 0; i < 4; ++i) t8[i] = fmaxf(t8[i], t8[i + 4]);
        float tmax = fmaxf(fmaxf(t8[0], t8[1]), fmaxf(t8[2], t8[3]));
        tmax = fmaxf(tmax, __shfl_xor(tmax, 32, 64));   // cross-half

        // T13 defer-max
        if (__any(tmax > m_run + DEFER_THR)) {
            float mnew = fmaxf(m_run, tmax);
            float scale = exp2f(m_run - mnew);
            m_run = mnew;
            l_run *= scale;
#pragma unroll
            for (int jn = 0; jn < 16; ++jn) {
                float sc = __shfl(scale, (jn & 3) + 8 * (jn >> 2) + 4 * hi, 64);
                accO[0][jn] *= sc;
                accO[1][jn] *= sc;
            }
        }
#pragma unroll
        for (int i = 0; i < 32; ++i) s[i] = exp2f(s[i] - m_run);
        // tree sum
        float u8[8];
#pragma unroll
        for (int i = 0; i < 8; ++i)
            u8[i] = (s[i] + s[i + 8]) + (s[i + 16] + s[i + 24]);
#pragma unroll
        for (int i = 0; i < 4; ++i) u8[i] += u8[i + 4];
        float psum = (u8[0] + u8[1]) + (u8[2] + u8[3]);
        psum += __shfl_xor(psum, 32, 64);               // cross-half
        l_run += psum;

        // V fragments: 1KB contiguous per load (fragment-major layout)
        v8s vf0[4], vf1[4];
#pragma unroll
        for (int ks = 0; ks < 4; ++ks) {
            vf0[ks] = *(const v8s*)(Vt + ks * 1024 + lq * 16 + hi * 8);
            vf1[ks] = *(const v8s*)(Vt + ks * 1024 + (lq + 32) * 16 + hi * 8);
        }

        // P -> PV A-operand in registers (cvt_pk + permlane32_swap; SSA-distinct)
        v8s PA[4];
#pragma unroll
        for (int t = 0; t < 2; ++t)
#pragma unroll
            for (int sf = 0; sf < 2; ++sf) {
                int base = t * 16 + sf * 8;
                unsigned x0 = cvtpk(s[base + 0], s[base + 1]);
                unsigned x1 = cvtpk(s[base + 2], s[base + 3]);
                unsigned y0 = cvtpk(s[base + 4], s[base + 5]);
                unsigned y1 = cvtpk(s[base + 6], s[base + 7]);
                asm volatile("v_permlane32_swap_b32 %0, %1" : "+v"(x0), "+v"(y0));
                asm volatile("v_permlane32_swap_b32 %0, %1" : "+v"(x1), "+v"(y1));
                v4u wv; wv[0] = x0; wv[1] = x1; wv[2] = y0; wv[3] = y1;
                union { v4u u; v8s s8; } cvt; cvt.u = wv;
                PA[t * 2 + sf] = cvt.s8;
            }

        __builtin_amdgcn_s_setprio(1);
#pragma unroll
        for (int ks = 0; ks < 4; ++ks) {
            accO[0] = MFMA32(PA[ks], vf0[ks], accO[0]);
            accO[1] = MFMA32(PA[ks], vf1[ks], accO[1]);
        }
        __builtin_amdgcn_s_setprio(0);
    };

    // main causal loop — no barriers, compiler-pipelined
    for (int kt = 0; kt < NT; ++kt)
        tile(kt, kt * 64 + 63 > qmin);

    // Rescue (per-wave): rows whose causal-valid keys are ALL masked tie
    // with future keys at exactly -CMASK (fp32 reference semantics).
    int kt = NT;
    while (kt < 32 && __any(m_run < -1e11f)) {
        tile(kt, true);
        ++kt;
    }

    // epilogue: write Ob at COMPACTED row (dense for out_gemm_c)
    float inv = 1.0f / l_run;
#pragma unroll
    for (int jn = 0; jn < 16; ++jn) {
        int rowq = (jn & 3) + 8 * (jn >> 2) + 4 * hi;
        float iv = __shfl(inv, rowq, 64);
        int jrow = cy + rowq;                          // compacted row
        if (jrow < nqv) {
            size_t base = (size_t)(b * S_LEN + jrow) * 1024 + hd * 64 + lq;
            O[base]      = f2bf(accO[0][jn] * iv);
            O[base + 32] = f2bf(accO[1][jn] * iv);
        }
    }
}

// ---------------- output projection, q-compacted (scatter + bias) ----------
// Same XCD map + dbuf/counted-vmcnt; 8-wave blocks like proj_all (R22).
__global__ __launch_bounds__(512)
void out_gemm_c(const short* __restrict__ A, const short* __restrict__ BT,
                const float* __restrict__ bias, const int* __restrict__ idx,
                const int* __restrict__ nq, float* __restrict__ out) {
    __shared__ short As[2][128 * 64];
    __shared__ short Bs[2][128 * 64];
    const int tid = threadIdx.x;
    const int l = tid & 63, w = tid >> 6;       // w in 0..7
    const int g = l >> 4, ql = l & 15;
    const int bid = blockIdx.x;
    const int y = (bid & 7) + 8 * (bid >> 6);   // M-tile (XCD-pinned)
    if (y >= 36) return;
    const int n0 = ((bid >> 3) & 7) * 128;      // N-tile (cycles fastest)
    const int b = y / 9;
    const int m0c = (y % 9) * 128;
    const int nqv = nq[b];
    if (m0c >= nqv) return;
    const int* idxb = idx + b * S_LEN;
    const int wr = w >> 2, wc = w & 3;          // 2x4 wave grid
    const int c8 = (((l & 7) ^ (l >> 3))) * 8;  // pre-swizzled source chunk

    v4f acc[4][2] = {};

    auto stage = [&](int kt, int buf) {
        const int kk = kt * 64;
#pragma unroll
        for (int i = 0; i < 2; ++i) {
            int ci = i * 512 + tid;
            int row = ci >> 3;
            async16((char*)As[buf] + (size_t)ci * 16,
                    A + (size_t)(b * S_LEN + m0c + row) * 1024 + kk + c8);
            async16((char*)Bs[buf] + (size_t)ci * 16,
                    BT + (size_t)(n0 + row) * 1024 + kk + c8);
        }
    };

    stage(0, 0);
    for (int kt = 0; kt < 16; ++kt) {
        __builtin_amdgcn_s_barrier();         // B1: buf (kt+1)&1 free to write
        __builtin_amdgcn_sched_barrier(0);
        if (kt + 1 < 16) {
            stage(kt + 1, (kt + 1) & 1);
            asm volatile("s_waitcnt vmcnt(4)" ::: "memory");  // kt's loads done
        } else {
            asm volatile("s_waitcnt vmcnt(0)" ::: "memory");
        }
        __builtin_amdgcn_sched_barrier(0);
        __builtin_amdgcn_s_barrier();         // B2: buf kt&1 staged (all waves)
        __builtin_amdgcn_sched_barrier(0);    // rule #18: no ds_read hoisting
        const short* Ab = As[kt & 1];
        const short* Bb = Bs[kt & 1];
#pragma unroll
        for (int ks = 0; ks < 2; ++ks) {
            v8s af[4], bfr[2];
#pragma unroll
            for (int mt = 0; mt < 4; ++mt)
                af[mt] = *(const v8s*)((char*)Ab +
                          swz(wr * 64 + mt * 16 + ql, ks * 64 + g * 16));
#pragma unroll
            for (int nt = 0; nt < 2; ++nt)
                bfr[nt] = *(const v8s*)((char*)Bb +
                          swz(wc * 32 + nt * 16 + ql, ks * 64 + g * 16));
#pragma unroll
            for (int mt = 0; mt < 4; ++mt)
#pragma unroll
                for (int nt = 0; nt < 2; ++nt)
                    acc[mt][nt] = MFMA16(af[mt], bfr[nt], acc[mt][nt]);
        }
    }

#pragma unroll
    for (int nt = 0; nt < 2; ++nt) {
        int col = n0 + wc * 32 + nt * 16 + ql;
        float bval = bias[col];
#pragma unroll
        for (int mt = 0; mt < 4; ++mt) {
#pragma unroll
            for (int r = 0; r < 4; ++r) {
                int jc = m0c + wr * 64 + mt * 16 + g * 4 + r;   // compacted row
                if (jc < nqv) {
                    int orig = idxb[jc];
                    out[(size_t)(b * S_LEN + orig) * 1024 + col] =
                        acc[mt][nt][r] + bval;
                }
            }
        }
    }
}

extern "C" void kernel_launch(void* const* d_in, const int* in_sizes, int n_in,
                              void* d_out, int out_size, void* d_ws, size_t ws_size,
                              hipStream_t stream) {
    (void)in_sizes; (void)n_in; (void)out_size; (void)ws_size;
    const float* q  = (const float*)d_in[0];
    const float* k  = (const float*)d_in[1];
    const float* v  = (const float*)d_in[2];
    const int* qmask = (const int*)d_in[3];
    const int* vmask = (const int*)d_in[4];
    const float* Wq = (const float*)d_in[5];
    const float* bq = (const float*)d_in[6];
    const float* Wk = (const float*)d_in[7];
    const float* bk = (const float*)d_in[8];
    const float* Wv = (const float*)d_in[9];
    const float* bv = (const float*)d_in[10];
    const float* Wo = (const float*)d_in[11];
    const float* bo = (const float*)d_in[12];
    float* out = (float*)d_out;

    char* ws = (char*)d_ws;
    const size_t MB = 1024 * 1024;
    short* Xq  = (short*)(ws + 0 * MB);
    short* Xk  = (short*)(ws + 16 * MB);
    short* Xv  = (short*)(ws + 32 * MB);
    short* WTq = (short*)(ws + 48 * MB);
    short* WTk = (short*)(ws + 50 * MB);
    short* WTv = (short*)(ws + 52 * MB);
    short* WTo = (short*)(ws + 54 * MB);
    short* QW  = (short*)(ws + 56 * MB);
    short* KF  = (short*)(ws + 72 * MB);
    short* VFb = (short*)(ws + 88 * MB);
    short* Ob  = (short*)(ws + 104 * MB);
    short* penC = (short*)(ws + 120 * MB);
    int* idxB  = (int*)(ws + 121 * MB);
    int* nqB   = (int*)(ws + 122 * MB);

    convert_all<<<dim3(4096, 4), 256, 0, stream>>>(q, k, v, Xq, Xk, Xv, out);
    transpose_all<<<dim3(32, 32, 4), 256, 0, stream>>>(Wq, Wk, Wv, Wo,
                                                       WTq, WTk, WTv, WTo);
    build_pen<<<32, 256, 0, stream>>>(vmask, penC);
    compact_qmask<<<NB, 256, 0, stream>>>(qmask, idxB, nqB);

    proj_all<<<dim3(512, 1, 3), 512, 0, stream>>>(Xk, Xv, Xq, WTk, WTv, WTq,
                                                  bk, bv, bq, idxB, nqB,
                                                  KF, VFb, QW);
    attn_kernel<<<dim3(64, 64), 64, 0, stream>>>(QW, KF, VFb, penC, idxB, nqB, Ob);
    out_gemm_c<<<320, 512, 0, stream>>>(Ob, WTo, bo, idxB, nqB, out);
}